// Round 2
// baseline (1301.602 us; speedup 1.0000x reference)
//
#include <hip/hip_runtime.h>
#include <hip/hip_bf16.h>

#define D 48
#define GNUM 64
#define HDIM 128
#define ODIM 12
#define BN_EPS 1e-5f

typedef _Float16 half4v __attribute__((ext_vector_type(4)));
typedef float f32x4 __attribute__((ext_vector_type(4)));

// v_mfma_f32_16x16x16_f16: A/B = 4 x f16 per lane, C/D = 4 x f32 per lane.
// NOTE: no __has_builtin gate -- it returns 0 in the host pass and breaks the build.
#define MFMA16(a, b, c) __builtin_amdgcn_mfma_f32_16x16x16f16((a), (b), (c), 0, 0, 0)

// ---------------- setup kernels ----------------

__global__ __launch_bounds__(256) void k_deg(const int* __restrict__ row, int* __restrict__ deg, int E) {
    int e = blockIdx.x * 256 + threadIdx.x;
    if (e < E) atomicAdd(&deg[row[e]], 1);
}

__global__ __launch_bounds__(256) void k_dinv(const int* __restrict__ deg, float* __restrict__ dinv, int N) {
    int i = blockIdx.x * 256 + threadIdx.x;
    if (i < N) dinv[i] = deg[i] > 0 ? rsqrtf((float)deg[i]) : 0.f;
}

__global__ __launch_bounds__(256) void k_scan1(const int* __restrict__ deg, int* __restrict__ incl,
                                               int* __restrict__ bsum, int N) {
    __shared__ int s[256];
    int i = blockIdx.x * 256 + threadIdx.x;
    s[threadIdx.x] = (i < N) ? deg[i] : 0;
    __syncthreads();
    for (int off = 1; off < 256; off <<= 1) {
        int t = (threadIdx.x >= off) ? s[threadIdx.x - off] : 0;
        __syncthreads();
        s[threadIdx.x] += t;
        __syncthreads();
    }
    if (i < N) incl[i] = s[threadIdx.x];
    if (threadIdx.x == 255) bsum[blockIdx.x] = s[255];
}

__global__ __launch_bounds__(512) void k_scan2(int* __restrict__ bsum, int nb) {
    __shared__ int s[512];
    int t = threadIdx.x;
    s[t] = (t < nb) ? bsum[t] : 0;
    __syncthreads();
    for (int off = 1; off < 512; off <<= 1) {
        int v = (t >= off) ? s[t - off] : 0;
        __syncthreads();
        s[t] += v;
        __syncthreads();
    }
    if (t < nb) bsum[t] = s[t];
}

__global__ __launch_bounds__(256) void k_scan3(const int* __restrict__ incl, const int* __restrict__ bsum,
                                               int* __restrict__ rowptr, int N) {
    int i = blockIdx.x * 256 + threadIdx.x;
    if (i < N) {
        int add = (blockIdx.x > 0) ? bsum[blockIdx.x - 1] : 0;
        rowptr[i + 1] = incl[i] + add;
    }
    if (i == 0) rowptr[0] = 0;
}

__global__ __launch_bounds__(256) void k_fill(const int* __restrict__ row, const int* __restrict__ col,
                                              const int* __restrict__ rowptr, int* __restrict__ fillc,
                                              const float* __restrict__ dinv, int2* __restrict__ epair, int E) {
    int e = blockIdx.x * 256 + threadIdx.x;
    if (e < E) {
        int r = row[e], c = col[e];
        int p = rowptr[r] + atomicAdd(&fillc[r], 1);
        epair[p] = make_int2(c, __float_as_int(dinv[c]));
    }
}

__global__ __launch_bounds__(256) void k_cvt(const float* __restrict__ x, _Float16* __restrict__ xh, int n4) {
    int i = blockIdx.x * 256 + threadIdx.x;
    if (i < n4) {
        float4 v = ((const float4*)x)[i];
        half4v h;
        h.x = (_Float16)v.x; h.y = (_Float16)v.y; h.z = (_Float16)v.z; h.w = (_Float16)v.w;
        ((half4v*)xh)[i] = h;
    }
}

// ---------------- gather kernels ----------------
// 4 slots x 16 lanes per node; 4-deep batched gathers for memory-level parallelism:
// one batch issues 4 independent epair loads then 4 independent feature-row loads,
// covering 16 edges (= the average degree) per iteration.

__global__ __launch_bounds__(256) void k_lhat(const _Float16* __restrict__ cur, const int* __restrict__ rowptr,
                                              const int2* __restrict__ epair, const float* __restrict__ dinv,
                                              _Float16* __restrict__ tx1, int N) {
    int lane = threadIdx.x & 63;
    int i = (blockIdx.x * 256 + threadIdx.x) >> 6;
    if (i >= N) return;
    int q = lane & 15, slot = lane >> 4;
    int qc = q < 12 ? q : 11;
    int s = rowptr[i], e = rowptr[i + 1];
    float a0 = 0.f, a1 = 0.f, a2 = 0.f, a3 = 0.f;
    int p = s + slot;
    for (; p + 12 < e; p += 16) {
        int2 e0 = epair[p], e1 = epair[p + 4], e2 = epair[p + 8], e3 = epair[p + 12];
        half4v h0 = *(const half4v*)(cur + (size_t)e0.x * D + qc * 4);
        half4v h1 = *(const half4v*)(cur + (size_t)e1.x * D + qc * 4);
        half4v h2 = *(const half4v*)(cur + (size_t)e2.x * D + qc * 4);
        half4v h3 = *(const half4v*)(cur + (size_t)e3.x * D + qc * 4);
        float w0 = __int_as_float(e0.y), w1 = __int_as_float(e1.y);
        float w2 = __int_as_float(e2.y), w3 = __int_as_float(e3.y);
        a0 += w0 * (float)h0.x + w1 * (float)h1.x + w2 * (float)h2.x + w3 * (float)h3.x;
        a1 += w0 * (float)h0.y + w1 * (float)h1.y + w2 * (float)h2.y + w3 * (float)h3.y;
        a2 += w0 * (float)h0.z + w1 * (float)h1.z + w2 * (float)h2.z + w3 * (float)h3.z;
        a3 += w0 * (float)h0.w + w1 * (float)h1.w + w2 * (float)h2.w + w3 * (float)h3.w;
    }
    for (; p < e; p += 4) {
        int2 ea = epair[p];
        float wa = __int_as_float(ea.y);
        half4v ha = *(const half4v*)(cur + (size_t)ea.x * D + qc * 4);
        a0 += wa * (float)ha.x; a1 += wa * (float)ha.y; a2 += wa * (float)ha.z; a3 += wa * (float)ha.w;
    }
    a0 += __shfl_xor(a0, 16); a1 += __shfl_xor(a1, 16); a2 += __shfl_xor(a2, 16); a3 += __shfl_xor(a3, 16);
    a0 += __shfl_xor(a0, 32); a1 += __shfl_xor(a1, 32); a2 += __shfl_xor(a2, 32); a3 += __shfl_xor(a3, 32);
    if (lane < 12) {
        float sc = -dinv[i];
        half4v o;
        o.x = (_Float16)(sc * a0); o.y = (_Float16)(sc * a1);
        o.z = (_Float16)(sc * a2); o.w = (_Float16)(sc * a3);
        *(half4v*)(tx1 + (size_t)i * D + lane * 4) = o;
    }
}

__global__ __launch_bounds__(256) void k_gather2(const _Float16* __restrict__ tx0, const _Float16* __restrict__ tx1,
                                                 const int* __restrict__ rowptr, const int2* __restrict__ epair,
                                                 const float* __restrict__ dinv, _Float16* __restrict__ tx2, int N) {
    int lane = threadIdx.x & 63;
    int i = (blockIdx.x * 256 + threadIdx.x) >> 6;
    if (i >= N) return;
    int q = lane & 15, slot = lane >> 4;
    int qc = q < 12 ? q : 11;
    int s = rowptr[i], e = rowptr[i + 1];
    float a0 = 0.f, a1 = 0.f, a2 = 0.f, a3 = 0.f;
    int p = s + slot;
    for (; p + 12 < e; p += 16) {
        int2 e0 = epair[p], e1 = epair[p + 4], e2 = epair[p + 8], e3 = epair[p + 12];
        half4v h0 = *(const half4v*)(tx1 + (size_t)e0.x * D + qc * 4);
        half4v h1 = *(const half4v*)(tx1 + (size_t)e1.x * D + qc * 4);
        half4v h2 = *(const half4v*)(tx1 + (size_t)e2.x * D + qc * 4);
        half4v h3 = *(const half4v*)(tx1 + (size_t)e3.x * D + qc * 4);
        float w0 = __int_as_float(e0.y), w1 = __int_as_float(e1.y);
        float w2 = __int_as_float(e2.y), w3 = __int_as_float(e3.y);
        a0 += w0 * (float)h0.x + w1 * (float)h1.x + w2 * (float)h2.x + w3 * (float)h3.x;
        a1 += w0 * (float)h0.y + w1 * (float)h1.y + w2 * (float)h2.y + w3 * (float)h3.y;
        a2 += w0 * (float)h0.z + w1 * (float)h1.z + w2 * (float)h2.z + w3 * (float)h3.z;
        a3 += w0 * (float)h0.w + w1 * (float)h1.w + w2 * (float)h2.w + w3 * (float)h3.w;
    }
    for (; p < e; p += 4) {
        int2 ea = epair[p];
        float wa = __int_as_float(ea.y);
        half4v ha = *(const half4v*)(tx1 + (size_t)ea.x * D + qc * 4);
        a0 += wa * (float)ha.x; a1 += wa * (float)ha.y; a2 += wa * (float)ha.z; a3 += wa * (float)ha.w;
    }
    a0 += __shfl_xor(a0, 16); a1 += __shfl_xor(a1, 16); a2 += __shfl_xor(a2, 16); a3 += __shfl_xor(a3, 16);
    a0 += __shfl_xor(a0, 32); a1 += __shfl_xor(a1, 32); a2 += __shfl_xor(a2, 32); a3 += __shfl_xor(a3, 32);
    if (lane < 12) {
        float sc = -2.f * dinv[i];
        half4v h0 = *(const half4v*)(tx0 + (size_t)i * D + lane * 4);
        half4v o;
        o.x = (_Float16)(sc * a0 - (float)h0.x); o.y = (_Float16)(sc * a1 - (float)h0.y);
        o.z = (_Float16)(sc * a2 - (float)h0.z); o.w = (_Float16)(sc * a3 - (float)h0.w);
        *(half4v*)(tx2 + (size_t)i * D + lane * 4) = o;
    }
}

// ---------------- dense: t = relu([tx0|tx1|tx2] @ W + b), MFMA + fused BN stats ----------------
// Per wave: one 16-node tile. A-frag: lane&15 = node, (lane>>4)*4+j = k (half4 global load).
// B-frag from LDS W^T: lane&15 = out-col, same k mapping.
// C/D: col = lane&15, row(node) = (lane>>4)*4 + i  [m89-verified 16x16 layout].

__global__ __launch_bounds__(256) void k_dense(const _Float16* __restrict__ tx0, const _Float16* __restrict__ tx1,
                                               const _Float16* __restrict__ tx2, const float* __restrict__ W,
                                               const float* __restrict__ b, _Float16* __restrict__ tbuf,
                                               float* __restrict__ bnst, int N) {
    __shared__ _Float16 WT[48][152];  // [col][k], padded stride
    __shared__ float bL[D];
    __shared__ float bns[2 * D];
    int t = threadIdx.x;
    for (int idx = t; idx < 144 * D; idx += 256) {
        int k = idx / D, c = idx % D;  // idx = k*48 + c
        WT[c][k] = (_Float16)W[idx];
    }
    if (t < D) bL[t] = b[t];
    if (t < 2 * D) bns[t] = 0.f;
    __syncthreads();

    int lane = t & 63, wave = t >> 6;
    int node0 = (blockIdx.x * 4 + wave) * 16;
    if (node0 < N) {
        int col = lane & 15, kg = lane >> 4;
        int nodeA = node0 + col;
        bool inA = nodeA < N;
        const _Float16* __restrict__ Xs0 = tx0 + (size_t)nodeA * D;
        const _Float16* __restrict__ Xs1 = tx1 + (size_t)nodeA * D;
        const _Float16* __restrict__ Xs2 = tx2 + (size_t)nodeA * D;
        const _Float16* __restrict__ Xs[3] = {Xs0, Xs1, Xs2};
        f32x4 acc0 = {}, acc1 = {}, acc2 = {};
#pragma unroll
        for (int s = 0; s < 3; ++s) {
#pragma unroll
            for (int kb = 0; kb < 48; kb += 16) {
                half4v a = {};
                if (inA) a = *(const half4v*)(Xs[s] + kb + kg * 4);
                int kk = s * 48 + kb + kg * 4;
                half4v b0 = *(const half4v*)&WT[col][kk];
                half4v b1 = *(const half4v*)&WT[16 + col][kk];
                half4v b2 = *(const half4v*)&WT[32 + col][kk];
                acc0 = MFMA16(a, b0, acc0);
                acc1 = MFMA16(a, b1, acc1);
                acc2 = MFMA16(a, b2, acc2);
            }
        }
        float s0 = 0.f, q0 = 0.f, s1 = 0.f, q1 = 0.f, s2 = 0.f, q2 = 0.f;
#pragma unroll
        for (int i = 0; i < 4; ++i) {
            int nd = node0 + kg * 4 + i;
            float v0 = fmaxf(acc0[i] + bL[col], 0.f);
            float v1 = fmaxf(acc1[i] + bL[16 + col], 0.f);
            float v2 = fmaxf(acc2[i] + bL[32 + col], 0.f);
            if (nd < N) {
                _Float16* o = tbuf + (size_t)nd * D;
                o[col] = (_Float16)v0;
                o[16 + col] = (_Float16)v1;
                o[32 + col] = (_Float16)v2;
                s0 += v0; q0 += v0 * v0;
                s1 += v1; q1 += v1 * v1;
                s2 += v2; q2 += v2 * v2;
            }
        }
        s0 += __shfl_xor(s0, 16); s0 += __shfl_xor(s0, 32);
        q0 += __shfl_xor(q0, 16); q0 += __shfl_xor(q0, 32);
        s1 += __shfl_xor(s1, 16); s1 += __shfl_xor(s1, 32);
        q1 += __shfl_xor(q1, 16); q1 += __shfl_xor(q1, 32);
        s2 += __shfl_xor(s2, 16); s2 += __shfl_xor(s2, 32);
        q2 += __shfl_xor(q2, 16); q2 += __shfl_xor(q2, 32);
        if (lane < 16) {
            atomicAdd(&bns[col], s0);      atomicAdd(&bns[D + col], q0);
            atomicAdd(&bns[16 + col], s1); atomicAdd(&bns[D + 16 + col], q1);
            atomicAdd(&bns[32 + col], s2); atomicAdd(&bns[D + 32 + col], q2);
        }
    }
    __syncthreads();
    if (t < 2 * D) atomicAdd(&bnst[t], bns[t]);
}

// ---------------- pool (BN scale/shift computed in-block from bnstats) ----------------

__global__ __launch_bounds__(256) void k_pool(const _Float16* __restrict__ tbuf, const int* __restrict__ rowptr,
                                              const int2* __restrict__ epair, const float* __restrict__ bnst,
                                              const float* __restrict__ gamma, const float* __restrict__ beta,
                                              float Ninv, _Float16* __restrict__ outh, int N) {
    __shared__ float ssL[2 * D];
    int t = threadIdx.x;
    if (t < D) {
        float mean = bnst[t] * Ninv;
        float var = fmaxf(bnst[D + t] * Ninv - mean * mean, 0.f);
        float sc = gamma[t] * rsqrtf(var + BN_EPS);
        ssL[t] = sc;
        ssL[D + t] = beta[t] - mean * sc;
    }
    __syncthreads();
    int lane = t & 63;
    int i = (blockIdx.x * 256 + t) >> 6;
    if (i >= N) return;
    int q = lane & 15, slot = lane >> 4;
    int qc = q < 12 ? q : 11;
    int s = rowptr[i], e = rowptr[i + 1];
    float m0 = -3.4e38f, m1 = -3.4e38f, m2 = -3.4e38f, m3 = -3.4e38f;
    float n0 = 3.4e38f, n1 = 3.4e38f, n2 = 3.4e38f, n3 = 3.4e38f;
    int p = s + slot;
    for (; p + 12 < e; p += 16) {
        int c0 = epair[p].x, c1 = epair[p + 4].x, c2 = epair[p + 8].x, c3 = epair[p + 12].x;
        half4v h0 = *(const half4v*)(tbuf + (size_t)c0 * D + qc * 4);
        half4v h1 = *(const half4v*)(tbuf + (size_t)c1 * D + qc * 4);
        half4v h2 = *(const half4v*)(tbuf + (size_t)c2 * D + qc * 4);
        half4v h3 = *(const half4v*)(tbuf + (size_t)c3 * D + qc * 4);
        float x00 = (float)h0.x, x01 = (float)h0.y, x02 = (float)h0.z, x03 = (float)h0.w;
        float x10 = (float)h1.x, x11 = (float)h1.y, x12 = (float)h1.z, x13 = (float)h1.w;
        float x20 = (float)h2.x, x21 = (float)h2.y, x22 = (float)h2.z, x23 = (float)h2.w;
        float x30 = (float)h3.x, x31 = (float)h3.y, x32 = (float)h3.z, x33 = (float)h3.w;
        m0 = fmaxf(m0, fmaxf(fmaxf(x00, x10), fmaxf(x20, x30)));
        m1 = fmaxf(m1, fmaxf(fmaxf(x01, x11), fmaxf(x21, x31)));
        m2 = fmaxf(m2, fmaxf(fmaxf(x02, x12), fmaxf(x22, x32)));
        m3 = fmaxf(m3, fmaxf(fmaxf(x03, x13), fmaxf(x23, x33)));
        n0 = fminf(n0, fminf(fminf(x00, x10), fminf(x20, x30)));
        n1 = fminf(n1, fminf(fminf(x01, x11), fminf(x21, x31)));
        n2 = fminf(n2, fminf(fminf(x02, x12), fminf(x22, x32)));
        n3 = fminf(n3, fminf(fminf(x03, x13), fminf(x23, x33)));
    }
    for (; p < e; p += 4) {
        int ca = epair[p].x;
        half4v ha = *(const half4v*)(tbuf + (size_t)ca * D + qc * 4);
        float a0 = (float)ha.x, a1 = (float)ha.y, a2 = (float)ha.z, a3 = (float)ha.w;
        m0 = fmaxf(m0, a0); m1 = fmaxf(m1, a1); m2 = fmaxf(m2, a2); m3 = fmaxf(m3, a3);
        n0 = fminf(n0, a0); n1 = fminf(n1, a1); n2 = fminf(n2, a2); n3 = fminf(n3, a3);
    }
    m0 = fmaxf(m0, __shfl_xor(m0, 16)); m1 = fmaxf(m1, __shfl_xor(m1, 16));
    m2 = fmaxf(m2, __shfl_xor(m2, 16)); m3 = fmaxf(m3, __shfl_xor(m3, 16));
    m0 = fmaxf(m0, __shfl_xor(m0, 32)); m1 = fmaxf(m1, __shfl_xor(m1, 32));
    m2 = fmaxf(m2, __shfl_xor(m2, 32)); m3 = fmaxf(m3, __shfl_xor(m3, 32));
    n0 = fminf(n0, __shfl_xor(n0, 16)); n1 = fminf(n1, __shfl_xor(n1, 16));
    n2 = fminf(n2, __shfl_xor(n2, 16)); n3 = fminf(n3, __shfl_xor(n3, 16));
    n0 = fminf(n0, __shfl_xor(n0, 32)); n1 = fminf(n1, __shfl_xor(n1, 32));
    n2 = fminf(n2, __shfl_xor(n2, 32)); n3 = fminf(n3, __shfl_xor(n3, 32));
    if (lane < 12) {
        float4 sc = *(const float4*)(ssL + lane * 4);
        float4 sh = *(const float4*)(ssL + D + lane * 4);
        half4v o;
        if (s == e) {
            o.x = (_Float16)0.f; o.y = (_Float16)0.f; o.z = (_Float16)0.f; o.w = (_Float16)0.f;
        } else {
            float v0 = (sc.x >= 0.f) ? sc.x * m0 + sh.x : sc.x * n0 + sh.x;
            float v1 = (sc.y >= 0.f) ? sc.y * m1 + sh.y : sc.y * n1 + sh.y;
            float v2 = (sc.z >= 0.f) ? sc.z * m2 + sh.z : sc.z * n2 + sh.z;
            float v3 = (sc.w >= 0.f) ? sc.w * m3 + sh.w : sc.w * n3 + sh.w;
            o.x = (_Float16)v0; o.y = (_Float16)v1; o.z = (_Float16)v2; o.w = (_Float16)v3;
        }
        *(half4v*)(outh + (size_t)i * D + lane * 4) = o;
    }
}

// ---------------- final pooling + MLP ----------------

__global__ __launch_bounds__(256) void k_gpool(const _Float16* __restrict__ outh, const int* __restrict__ batch,
                                               float* __restrict__ g, int N, int chunk) {
    int lane = threadIdx.x & 63;
    int wid = (blockIdx.x * 256 + threadIdx.x) >> 6;
    int start = wid * chunk;
    if (start >= N || lane >= 12) return;
    int end = start + chunk;
    if (end > N) end = N;
    int curb = batch[start];
    float a0 = 0.f, a1 = 0.f, a2 = 0.f, a3 = 0.f;
    for (int i = start; i < end; ++i) {
        int bi = batch[i];
        if (bi != curb) {
            atomicAdd(&g[curb * D + lane * 4 + 0], a0); atomicAdd(&g[curb * D + lane * 4 + 1], a1);
            atomicAdd(&g[curb * D + lane * 4 + 2], a2); atomicAdd(&g[curb * D + lane * 4 + 3], a3);
            curb = bi; a0 = a1 = a2 = a3 = 0.f;
        }
        half4v h = *(const half4v*)(outh + (size_t)i * D + lane * 4);
        a0 += (float)h.x; a1 += (float)h.y; a2 += (float)h.z; a3 += (float)h.w;
    }
    atomicAdd(&g[curb * D + lane * 4 + 0], a0); atomicAdd(&g[curb * D + lane * 4 + 1], a1);
    atomicAdd(&g[curb * D + lane * 4 + 2], a2); atomicAdd(&g[curb * D + lane * 4 + 3], a3);
}

__global__ __launch_bounds__(256) void k_mlp(const float* __restrict__ g, const float* __restrict__ W1,
                                             const float* __restrict__ b1, const float* __restrict__ W2,
                                             const float* __restrict__ b2, float* __restrict__ out) {
    __shared__ float gL[GNUM * D];
    __shared__ float hL[GNUM * HDIM];
    __shared__ float W1L[D * HDIM];
    int t = threadIdx.x;
    for (int i = t; i < GNUM * D; i += 256) gL[i] = g[i];
    for (int i = t; i < D * HDIM; i += 256) W1L[i] = W1[i];
    __syncthreads();
    for (int i = t; i < GNUM * HDIM; i += 256) {
        int gi = i >> 7, hj = i & 127;
        float a = b1[hj];
        for (int k = 0; k < D; ++k) a += gL[gi * D + k] * W1L[k * HDIM + hj];
        hL[i] = fmaxf(a, 0.f);
    }
    __syncthreads();
    for (int i = t; i < GNUM * ODIM; i += 256) {
        int gi = i / ODIM, oj = i % ODIM;
        float a = b2[oj];
        for (int k = 0; k < HDIM; ++k) a += hL[gi * HDIM + k] * W2[k * ODIM + oj];
        out[i] = a;
    }
}

// ---------------- launch ----------------

extern "C" void kernel_launch(void* const* d_in, const int* in_sizes, int n_in,
                              void* d_out, int out_size, void* d_ws, size_t ws_size,
                              hipStream_t stream) {
    const float* x     = (const float*)d_in[0];
    const int*   ei    = (const int*)d_in[1];
    const int*   batch = (const int*)d_in[2];
    const float* W     = (const float*)d_in[4];
    const float* b     = (const float*)d_in[5];
    const float* gamma = (const float*)d_in[6];
    const float* beta  = (const float*)d_in[7];
    const float* W1    = (const float*)d_in[8];
    const float* b1    = (const float*)d_in[9];
    const float* W2    = (const float*)d_in[10];
    const float* b2    = (const float*)d_in[11];

    int N = in_sizes[0] / D;
    int E = in_sizes[1] / 2;
    const int* row = ei;
    const int* col = ei + E;

    char* w = (char*)d_ws;
    auto alloc = [&](size_t bytes) { char* p = w; w += (bytes + 255) & ~(size_t)255; return p; };
    int*       deg     = (int*)alloc((size_t)N * 4);
    float*     dinv    = (float*)alloc((size_t)N * 4);
    int*       fillc   = (int*)alloc((size_t)N * 4);
    int*       incl    = (int*)alloc((size_t)N * 4);
    int*       bsum    = (int*)alloc(4096);
    int*       rowptr  = (int*)alloc((size_t)(N + 1) * 4);
    int2*      epair   = (int2*)alloc((size_t)E * 8);
    _Float16*  xh      = (_Float16*)alloc((size_t)N * D * 2 + 64);
    _Float16*  tx1h    = (_Float16*)alloc((size_t)N * D * 2 + 64);
    _Float16*  tx2h    = (_Float16*)alloc((size_t)N * D * 2 + 64);
    _Float16*  tbufh   = (_Float16*)alloc((size_t)N * D * 2 + 64);
    _Float16*  outh    = (_Float16*)alloc((size_t)N * D * 2 + 64);
    float*     bnstats = (float*)alloc(5 * 2 * D * 4);   // per-step slices, zeroed once
    float*     g       = (float*)alloc((size_t)GNUM * D * 4);

    (void)hipMemsetAsync(deg, 0, (size_t)N * 4, stream);
    (void)hipMemsetAsync(fillc, 0, (size_t)N * 4, stream);
    (void)hipMemsetAsync(bnstats, 0, 5 * 2 * D * 4, stream);
    (void)hipMemsetAsync(g, 0, (size_t)GNUM * D * 4, stream);

    int nbE = (E + 255) / 256;
    int nbN = (N + 255) / 256;

    k_deg<<<nbE, 256, 0, stream>>>(row, deg, E);
    k_dinv<<<nbN, 256, 0, stream>>>(deg, dinv, N);
    k_scan1<<<nbN, 256, 0, stream>>>(deg, incl, bsum, N);
    k_scan2<<<1, 512, 0, stream>>>(bsum, nbN);
    k_scan3<<<nbN, 256, 0, stream>>>(incl, bsum, rowptr, N);
    k_fill<<<nbE, 256, 0, stream>>>(row, col, rowptr, fillc, dinv, epair, E);
    int n4 = N * D / 4;
    k_cvt<<<(n4 + 255) / 256, 256, 0, stream>>>(x, xh, n4);

    int nbWave = (N * 64 + 255) / 256;
    int nbDense = (((N + 15) / 16) + 3) / 4;  // 16-node tiles, 4 waves/block
    float Ninv = 1.f / (float)N;
    const _Float16* cur = xh;
    for (int step = 0; step < 5; ++step) {
        float* bnst = bnstats + step * 2 * D;
        k_lhat<<<nbWave, 256, 0, stream>>>(cur, rowptr, epair, dinv, tx1h, N);
        k_gather2<<<nbWave, 256, 0, stream>>>(cur, tx1h, rowptr, epair, dinv, tx2h, N);
        k_dense<<<nbDense, 256, 0, stream>>>(cur, tx1h, tx2h, W, b, tbufh, bnst, N);
        k_pool<<<nbWave, 256, 0, stream>>>(tbufh, rowptr, epair, bnst, gamma, beta, Ninv, outh, N);
        cur = outh;
    }

    int chunk = 32;
    int nwaves = (N + chunk - 1) / chunk;
    int nbG = (nwaves * 64 + 255) / 256;
    k_gpool<<<nbG, 256, 0, stream>>>(outh, batch, g, N, chunk);
    k_mlp<<<1, 256, 0, stream>>>(g, W1, b1, W2, b2, (float*)d_out);
}